// Round 6
// baseline (102.751 us; speedup 1.0000x reference)
//
#include <hip/hip_runtime.h>

// Gated pair-bias attention (AlphaFold-style), MI355X gfx950.
// B=8 S=1024 D=256 H=8 DH=32. All GEMM-shaped work in bf16 MFMA 16x16x32.
//
// Pipeline:
//   proj_kernel   : qh=(q Wq^T)*norm, sig=sigmoid(q Wg^T + bg), kh=k Wk^T,
//                   vhT = (v Wv^T)^T per (b,h)  [dh][s]               (bf16 in ws)
//   attn_kernel   : flash attention, swapped-operand form (S^T and O^T),
//                   8 waves = 2 kv-halves x 4 q-subtiles; in-LDS partial merge;
//                   defer-max softmax; 32 waves/CU                     (bf16 in ws)
//   outproj_kernel: out = og Wo^T  (fp32 to d_out)

typedef __attribute__((ext_vector_type(4))) float f32x4;
typedef __attribute__((ext_vector_type(8))) unsigned short u16x8;
typedef __attribute__((ext_vector_type(4))) unsigned short u16x4;
typedef __attribute__((ext_vector_type(8))) __bf16 bf16x8;
typedef __attribute__((ext_vector_type(4))) __bf16 bf16x4;

#define BB 8
#define SS 1024
#define DD 256
#define HH 8
#define DHD 32

__device__ __forceinline__ float b2f(unsigned short s) {
  unsigned u = ((unsigned)s) << 16;
  return __builtin_bit_cast(float, u);
}
__device__ __forceinline__ f32x4 mfma16(u16x8 a, u16x8 b, f32x4 c) {
  return __builtin_amdgcn_mfma_f32_16x16x32_bf16(
      __builtin_bit_cast(bf16x8, a), __builtin_bit_cast(bf16x8, b), c, 0, 0, 0);
}

// ---------------------------------------------------------------------------
// Projections: C[8192,256] = A[8192,256] * W[256,256]^T  (einsum bsd,ed->bse)
// grid (128 row-tiles, 4 col-tiles, 4 slots), 256 threads (4 waves).
// Tile 64x64, K-step 32. LDS chunks (16B) XOR-swizzled: chunk ^= (row>>1)&3.
// slot 3 (v) stores TRANSPOSED per (b,h): vhT[((b*H+h)*DH+dh)*S + s].
// ---------------------------------------------------------------------------
__global__ __launch_bounds__(256) void proj_kernel(
    const float* __restrict__ q, const float* __restrict__ k,
    const float* __restrict__ v,
    const float* __restrict__ Wq, const float* __restrict__ Wg,
    const float* __restrict__ Wk, const float* __restrict__ Wv,
    const float* __restrict__ bg,
    unsigned short* __restrict__ qh, unsigned short* __restrict__ kh,
    unsigned short* __restrict__ vhT, unsigned short* __restrict__ sig) {
  const int slot = blockIdx.z;
  const float* A = (slot <= 1) ? q : (slot == 2 ? k : v);
  const float* W = (slot == 0) ? Wq : (slot == 1 ? Wg : (slot == 2 ? Wk : Wv));
  const int row0 = blockIdx.x * 64, col0 = blockIdx.y * 64;
  const int tid = threadIdx.x;
  const int w = tid >> 6, lane = tid & 63, g = lane >> 4, c = lane & 15;
  const int sr = tid >> 2, sc = tid & 3;   // staging: row 0..63, chunk 0..3

  __shared__ alignas(16) unsigned short As[64 * 32];
  __shared__ alignas(16) unsigned short Ws[64 * 32];

  const f32x4 zero = {0.f, 0.f, 0.f, 0.f};
  f32x4 acc[4] = {zero, zero, zero, zero};

  for (int kk = 0; kk < 8; ++kk) {
    __syncthreads();
    {
      const float* ap = A + (size_t)(row0 + sr) * DD + kk * 32 + sc * 8;
      f32x4 f0 = *(const f32x4*)ap;
      f32x4 f1 = *(const f32x4*)(ap + 4);
      bf16x8 a8;
#pragma unroll
      for (int j = 0; j < 4; ++j) { a8[j] = (__bf16)f0[j]; a8[j + 4] = (__bf16)f1[j]; }
      ((u16x8*)As)[sr * 4 + (sc ^ ((sr >> 1) & 3))] = __builtin_bit_cast(u16x8, a8);

      const float* wp = W + (size_t)(col0 + sr) * DD + kk * 32 + sc * 8;
      f32x4 w0 = *(const f32x4*)wp;
      f32x4 w1 = *(const f32x4*)(wp + 4);
      bf16x8 w8;
#pragma unroll
      for (int j = 0; j < 4; ++j) { w8[j] = (__bf16)w0[j]; w8[j + 4] = (__bf16)w1[j]; }
      ((u16x8*)Ws)[sr * 4 + (sc ^ ((sr >> 1) & 3))] = __builtin_bit_cast(u16x8, w8);
    }
    __syncthreads();
    const int arow = 16 * w + c;
    u16x8 af = ((u16x8*)As)[arow * 4 + (g ^ ((arow >> 1) & 3))];
#pragma unroll
    for (int n = 0; n < 4; ++n) {
      const int brow = 16 * n + c;
      u16x8 wf = ((u16x8*)Ws)[brow * 4 + (g ^ ((brow >> 1) & 3))];
      acc[n] = mfma16(af, wf, acc[n]);
    }
  }

  // D layout: row = 4*(lane>>4)+r, col = lane&15 (m89-verified)
  if (slot == 3) {
    // transposed store: vhT[(b*256 + col)*1024 + s], rows r are consecutive s
    const int row_base = row0 + 16 * w + 4 * g;
    const int bb = row_base >> 10;
    const int s0 = row_base & 1023;
#pragma unroll
    for (int n = 0; n < 4; ++n) {
      const int col = col0 + 16 * n + c;
      bf16x4 pv;
#pragma unroll
      for (int r = 0; r < 4; ++r) pv[r] = (__bf16)acc[n][r];
      *(u16x4*)(vhT + (size_t)(bb * 256 + col) * SS + s0) =
          __builtin_bit_cast(u16x4, pv);
    }
  } else {
#pragma unroll
    for (int n = 0; n < 4; ++n) {
#pragma unroll
      for (int r = 0; r < 4; ++r) {
        const int row = row0 + 16 * w + 4 * g + r;
        const int col = col0 + 16 * n + c;
        const size_t idx = (size_t)row * DD + col;
        const float val = acc[n][r];
        if (slot == 0)
          qh[idx] = __builtin_bit_cast(unsigned short,
                        (__bf16)(val * 0.17677669529663687f));  // DH^-0.5
        else if (slot == 1)
          sig[idx] = __builtin_bit_cast(unsigned short,
                         (__bf16)(1.0f / (1.0f + __expf(-(val + bg[col])))));
        else
          kh[idx] = __builtin_bit_cast(unsigned short, (__bf16)val);
      }
    }
  }
}

// ---------------------------------------------------------------------------
// Flash attention, swapped-operand form. 1D grid 1024 blocks, 512 threads =
// 8 waves: grp = w>>2 picks kv half [grp*512, +512), wq = w&3 picks 16 q rows.
// XCD swizzle: widx = (bid&7)*128 + bid>>3; h = widx>>7 -> each XCD owns one
// head (bias slice L2-resident; FETCH ~31MB confirmed r4/r5).
// S^T = mfma(K, Q): lane holds S[q=c][kv=16t+4g+r] -> softmax lane-local.
// O^T = mfma(V^T, P^T): acc[dt][r] = O^T[dh=16dt+4g+r][q=c].
// Each group: single-buffered K [64][32] + V^T [32][64] LDS (XOR-swizzled),
// reg-staged prefetch, 2 barriers/tile, 8 tiles. Partials merged in LDS:
// M=max(m0,m1); O=(e^{m0-M}O0+e^{m1-M}O1)/(l0 e^{m0-M}+l1 e^{m1-M}).
// Defer-max (T13): common path has zero cross-lane ops.
// ---------------------------------------------------------------------------
__global__ __launch_bounds__(512, 8) void attn_kernel(
    const unsigned short* __restrict__ qh, const unsigned short* __restrict__ kh,
    const unsigned short* __restrict__ vhT, const unsigned short* __restrict__ sig,
    const float* __restrict__ mask, const float* __restrict__ bias,
    unsigned short* __restrict__ og) {
  const int bid = blockIdx.x;
  const int widx = (bid & 7) * 128 + (bid >> 3);
  const int h = widx >> 7, b = (widx >> 4) & 7, qt = widx & 15;
  const int tid = threadIdx.x;
  const int w = tid >> 6, lane = tid & 63, g = lane >> 4, c = lane & 15;
  const int grp = w >> 2, wq = w & 3;

  __shared__ alignas(16) unsigned short Ks[2][64 * 32];   // [kv][dh] swizzled
  __shared__ alignas(16) unsigned short Vt[2][32 * 64];   // [dh][kv] swizzled
  __shared__ alignas(16) unsigned short Ps[8][16 * 64];   // per-wave P tile
  __shared__ float MLs[4][16][2];                         // grp1 (m,l) per q
  u16x8* Ks16 = (u16x8*)Ks[grp];
  u16x8* Vt16 = (u16x8*)Vt[grp];
  unsigned short* P = Ps[w];

  const int q0 = qt * 64 + wq * 16;
  // Q fragment (B operand): B[col=c][k=8g+i] = Q[q0+c][dh=8g+i]
  const u16x8 qf =
      *(const u16x8*)(qh + (size_t)(b * SS + q0 + c) * DD + h * DHD + g * 8);

  const f32x4 zero = {0.f, 0.f, 0.f, 0.f};
  f32x4 acc[2] = {zero, zero};
  float m_r = -1e30f, l_r = 0.f;   // partial softmax state (this lane's kv set)

  const int kvbase = grp * 512;
  const float* maskb = mask + b * SS + kvbase;
  const float* biasb = bias + (size_t)(h * SS + q0 + c) * SS + kvbase;

  // staging: 256 threads per group each own one 16B chunk of K and V
  const int ltid = tid & 255;
  const int krow = ltid >> 2, kj = ltid & 3;   // K: 64 rows x 4 chunks
  const int vrow = ltid >> 3, vj = ltid & 7;   // V: 32 rows x 8 chunks
  const unsigned short* kg =
      kh + (size_t)(b * SS + kvbase + krow) * DD + h * DHD + kj * 8;
  const unsigned short* vg =
      vhT + (size_t)((b * HH + h) * DHD + vrow) * SS + kvbase + vj * 8;
  const int kslot = krow * 4 + (kj ^ ((krow >> 1) & 3));
  const int vslot = vrow * 8 + (vj ^ (vrow & 7));

  // prologue: stage tile 0
  Ks16[kslot] = *(const u16x8*)kg;
  Vt16[vslot] = *(const u16x8*)vg;
  __syncthreads();

#pragma unroll 1
  for (int kt = 0; kt < 8; ++kt) {
    const int kv0 = kt * 64;
    // next tile's global loads issue early; vmcnt waits land at the ds_write
    u16x8 kreg, vreg;
    if (kt < 7) {
      kreg = *(const u16x8*)(kg + (size_t)(kv0 + 64) * DD);
      vreg = *(const u16x8*)(vg + kv0 + 64);
    }

    // S^T tile: sv[t][r] = S[q=c][kv=kvbase+kv0+16t+4g+r]
    f32x4 sv[4];
#pragma unroll
    for (int t = 0; t < 4; ++t) {
      const u16x8 kf = Ks16[(16 * t + c) * 4 + (g ^ ((c >> 1) & 3))];
      sv[t] = mfma16(kf, qf, zero);
    }
    // + mask + pair bias (direct f32x4 loads; TLP hides L2 latency)
#pragma unroll
    for (int t = 0; t < 4; ++t) {
      const f32x4 bi = *(const f32x4*)(biasb + kv0 + 16 * t + 4 * g);
      const f32x4 mk = *(const f32x4*)(maskb + kv0 + 16 * t + 4 * g);
      sv[t] += bi + mk;
    }
    // defer-max softmax (T13): common path = local max + exp only
    float pm = fmaxf(fmaxf(sv[0][0], sv[0][1]), fmaxf(sv[0][2], sv[0][3]));
#pragma unroll
    for (int t = 1; t < 4; ++t)
      pm = fmaxf(pm, fmaxf(fmaxf(sv[t][0], sv[t][1]), fmaxf(sv[t][2], sv[t][3])));
    if (!__all(pm - m_r <= 8.0f)) {          // fires at kt=0, then ~never
      float mx = fmaxf(pm, __shfl_xor(pm, 16));
      mx = fmaxf(mx, __shfl_xor(mx, 32));
      const float mnew = fmaxf(m_r, mx);
      const float scale = __expf(m_r - mnew);
      l_r *= scale;
      acc[0] *= scale;
      acc[1] *= scale;
      m_r = mnew;
    }
    float ps = 0.f;
#pragma unroll
    for (int t = 0; t < 4; ++t)
#pragma unroll
      for (int r = 0; r < 4; ++r) {
        const float p = __expf(sv[t][r] - m_r);
        sv[t][r] = p;
        ps += p;
      }
    l_r += ps;
    // P -> per-wave LDS, 16B-chunk XOR swizzle
#pragma unroll
    for (int t = 0; t < 4; ++t) {
      bf16x4 pv;
#pragma unroll
      for (int r = 0; r < 4; ++r) pv[r] = (__bf16)sv[t][r];
      const int n = 2 * t + (g >> 1);
      *(u16x4*)(P + c * 64 + ((n ^ (c & 7)) << 3) + ((g & 1) << 2)) =
          __builtin_bit_cast(u16x4, pv);
    }
    // O^T += V^T P^T  (wave-internal LDS RAW; compiler inserts lgkmcnt)
#pragma unroll
    for (int s2 = 0; s2 < 2; ++s2) {
      const u16x8 pf =
          *(const u16x8*)(P + c * 64 + (((4 * s2 + g) ^ (c & 7)) << 3));
#pragma unroll
      for (int dt = 0; dt < 2; ++dt) {
        const u16x8 vf = Vt16[(16 * dt + c) * 8 + ((s2 * 4 + g) ^ (c & 7))];
        acc[dt] = mfma16(vf, pf, acc[dt]);
      }
    }
    // publish next tile
    if (kt < 7) {
      __syncthreads();            // everyone in both groups done reading
      Ks16[kslot] = kreg;
      Vt16[vslot] = vreg;
      __syncthreads();            // next tile visible
    }
  }

  // combine partial l across the 4 g-lanes (same q=c)
  float l_w = l_r + __shfl_xor(l_r, 16);
  l_w += __shfl_xor(l_w, 32);

  // merge the two kv-half partials through LDS (reuse Ps)
  if (grp == 1) {
    float* MB = (float*)Ps[w];    // 16q x 32dh f32 = 2KB, chunk-swizzled
#pragma unroll
    for (int dt = 0; dt < 2; ++dt)
#pragma unroll
      for (int r = 0; r < 4; ++r)
        MB[c * 32 + (((4 * dt + g) ^ (c & 7)) << 2) + r] = acc[dt][r];
    if (g == 0) { MLs[wq][c][0] = m_r; MLs[wq][c][1] = l_w; }
  }
  __syncthreads();
  if (grp == 0) {
    const float m1 = MLs[wq][c][0], l1 = MLs[wq][c][1];
    const float* MB = (const float*)Ps[w + 4];
    const float M = fmaxf(m_r, m1);
    const float e0 = __expf(m_r - M), e1 = __expf(m1 - M);
    const float inv = 1.0f / (l_w * e0 + l1 * e1);
#pragma unroll
    for (int dt = 0; dt < 2; ++dt) {
      const f32x4 a1 =
          *(const f32x4*)(MB + c * 32 + (((4 * dt + g) ^ (c & 7)) << 2));
      const size_t idx =
          (size_t)(b * SS + q0 + c) * DD + h * DHD + 16 * dt + 4 * g;
      const u16x4 sg = *(const u16x4*)(sig + idx);
      bf16x4 ov;
#pragma unroll
      for (int r = 0; r < 4; ++r)
        ov[r] = (__bf16)((acc[dt][r] * e0 + a1[r] * e1) * inv * b2f(sg[r]));
      *(u16x4*)(og + idx) = __builtin_bit_cast(u16x4, ov);
    }
  }
}

// ---------------------------------------------------------------------------
// Output projection: out[8192,256] = og[8192,256] * Wo[256,256]^T (fp32 out)
// ---------------------------------------------------------------------------
__global__ __launch_bounds__(256) void outproj_kernel(
    const unsigned short* __restrict__ og, const float* __restrict__ Wo,
    float* __restrict__ out) {
  const int row0 = blockIdx.x * 64, col0 = blockIdx.y * 64;
  const int tid = threadIdx.x;
  const int w = tid >> 6, lane = tid & 63, g = lane >> 4, c = lane & 15;
  const int sr = tid >> 2, sc = tid & 3;

  __shared__ alignas(16) unsigned short As[64 * 32];
  __shared__ alignas(16) unsigned short Ws[64 * 32];

  const f32x4 zero = {0.f, 0.f, 0.f, 0.f};
  f32x4 acc[4] = {zero, zero, zero, zero};

  for (int kk = 0; kk < 8; ++kk) {
    __syncthreads();
    {
      const unsigned short* ap = og + (size_t)(row0 + sr) * DD + kk * 32 + sc * 8;
      ((u16x8*)As)[sr * 4 + (sc ^ ((sr >> 1) & 3))] = *(const u16x8*)ap;

      const float* wp = Wo + (size_t)(col0 + sr) * DD + kk * 32 + sc * 8;
      f32x4 w0 = *(const f32x4*)wp;
      f32x4 w1 = *(const f32x4*)(wp + 4);
      bf16x8 w8;
#pragma unroll
      for (int j = 0; j < 4; ++j) { w8[j] = (__bf16)w0[j]; w8[j + 4] = (__bf16)w1[j]; }
      ((u16x8*)Ws)[sr * 4 + (sc ^ ((sr >> 1) & 3))] = __builtin_bit_cast(u16x8, w8);
    }
    __syncthreads();
    const int arow = 16 * w + c;
    u16x8 af = ((u16x8*)As)[arow * 4 + (g ^ ((arow >> 1) & 3))];
#pragma unroll
    for (int n = 0; n < 4; ++n) {
      const int brow = 16 * n + c;
      u16x8 wf = ((u16x8*)Ws)[brow * 4 + (g ^ ((brow >> 1) & 3))];
      acc[n] = mfma16(af, wf, acc[n]);
    }
  }

#pragma unroll
  for (int n = 0; n < 4; ++n) {
#pragma unroll
    for (int r = 0; r < 4; ++r) {
      const int row = row0 + 16 * w + 4 * g + r;
      const int col = col0 + 16 * n + c;
      out[(size_t)row * DD + col] = acc[n][r];
    }
  }
}

extern "C" void kernel_launch(void* const* d_in, const int* in_sizes, int n_in,
                              void* d_out, int out_size, void* d_ws,
                              size_t ws_size, hipStream_t stream) {
  const float* q    = (const float*)d_in[0];
  const float* k    = (const float*)d_in[1];
  const float* v    = (const float*)d_in[2];
  const float* mask = (const float*)d_in[3];
  const float* bias = (const float*)d_in[4];
  const float* Wq   = (const float*)d_in[5];
  const float* Wk   = (const float*)d_in[6];
  const float* Wv   = (const float*)d_in[7];
  const float* Wg   = (const float*)d_in[8];
  const float* bg   = (const float*)d_in[9];
  const float* Wo   = (const float*)d_in[10];
  float* out = (float*)d_out;

  char* ws = (char*)d_ws;
  unsigned short* qh  = (unsigned short*)(ws);               // 4 MB bf16
  unsigned short* kh  = (unsigned short*)(ws + (4u << 20));  // 4 MB
  unsigned short* vhT = (unsigned short*)(ws + (8u << 20));  // 4 MB (transposed)
  unsigned short* sig = (unsigned short*)(ws + (12u << 20)); // 4 MB
  unsigned short* og  = (unsigned short*)(ws + (16u << 20)); // 4 MB

  hipLaunchKernelGGL(proj_kernel, dim3(128, 4, 4), dim3(256), 0, stream,
                     q, k, v, Wq, Wg, Wk, Wv, bg, qh, kh, vhT, sig);
  hipLaunchKernelGGL(attn_kernel, dim3(1024), dim3(512), 0, stream,
                     qh, kh, vhT, sig, mask, bias, og);
  hipLaunchKernelGGL(outproj_kernel, dim3(128, 4), dim3(256), 0, stream,
                     og, Wo, out);
}

// Round 7
// 85.579 us; speedup vs baseline: 1.2007x; 1.2007x over previous
//
#include <hip/hip_runtime.h>

// Gated pair-bias attention (AlphaFold-style), MI355X gfx950.
// B=8 S=1024 D=256 H=8 DH=32. All GEMM-shaped work in bf16 MFMA 16x16x32.
//
// Pipeline:
//   proj_kernel   : qh=(q Wq^T)*norm, sig=sigmoid(q Wg^T + bg), kh=k Wk^T,
//                   vhT = (v Wv^T)^T per (b,h)  [dh][s]               (bf16 in ws)
//   attn_kernel   : flash attention, swapped-operand form (S^T and O^T),
//                   8 waves = 2 kv-halves x 4 q-subtiles; in-LDS partial merge;
//                   defer-max softmax. launch_bounds(512,4): NO SPILL (r6
//                   lesson: (512,8) capped VGPR at 64 -> scratch traffic).
//   outproj_kernel: out = og Wo^T  (fp32 to d_out)

typedef __attribute__((ext_vector_type(4))) float f32x4;
typedef __attribute__((ext_vector_type(8))) unsigned short u16x8;
typedef __attribute__((ext_vector_type(4))) unsigned short u16x4;
typedef __attribute__((ext_vector_type(8))) __bf16 bf16x8;
typedef __attribute__((ext_vector_type(4))) __bf16 bf16x4;

#define BB 8
#define SS 1024
#define DD 256
#define HH 8
#define DHD 32

__device__ __forceinline__ float b2f(unsigned short s) {
  unsigned u = ((unsigned)s) << 16;
  return __builtin_bit_cast(float, u);
}
__device__ __forceinline__ f32x4 mfma16(u16x8 a, u16x8 b, f32x4 c) {
  return __builtin_amdgcn_mfma_f32_16x16x32_bf16(
      __builtin_bit_cast(bf16x8, a), __builtin_bit_cast(bf16x8, b), c, 0, 0, 0);
}

// ---------------------------------------------------------------------------
// Projections: C[8192,256] = A[8192,256] * W[256,256]^T  (einsum bsd,ed->bse)
// grid (128 row-tiles, 4 col-tiles, 4 slots), 256 threads (4 waves).
// Tile 64x64, K-step 32. LDS chunks (16B) XOR-swizzled: chunk ^= (row>>1)&3.
// slot 3 (v) stores TRANSPOSED per (b,h): vhT[((b*H+h)*DH+dh)*S + s].
// ---------------------------------------------------------------------------
__global__ __launch_bounds__(256) void proj_kernel(
    const float* __restrict__ q, const float* __restrict__ k,
    const float* __restrict__ v,
    const float* __restrict__ Wq, const float* __restrict__ Wg,
    const float* __restrict__ Wk, const float* __restrict__ Wv,
    const float* __restrict__ bg,
    unsigned short* __restrict__ qh, unsigned short* __restrict__ kh,
    unsigned short* __restrict__ vhT, unsigned short* __restrict__ sig) {
  const int slot = blockIdx.z;
  const float* A = (slot <= 1) ? q : (slot == 2 ? k : v);
  const float* W = (slot == 0) ? Wq : (slot == 1 ? Wg : (slot == 2 ? Wk : Wv));
  const int row0 = blockIdx.x * 64, col0 = blockIdx.y * 64;
  const int tid = threadIdx.x;
  const int w = tid >> 6, lane = tid & 63, g = lane >> 4, c = lane & 15;
  const int sr = tid >> 2, sc = tid & 3;   // staging: row 0..63, chunk 0..3

  __shared__ alignas(16) unsigned short As[64 * 32];
  __shared__ alignas(16) unsigned short Ws[64 * 32];

  const f32x4 zero = {0.f, 0.f, 0.f, 0.f};
  f32x4 acc[4] = {zero, zero, zero, zero};

  for (int kk = 0; kk < 8; ++kk) {
    __syncthreads();
    {
      const float* ap = A + (size_t)(row0 + sr) * DD + kk * 32 + sc * 8;
      f32x4 f0 = *(const f32x4*)ap;
      f32x4 f1 = *(const f32x4*)(ap + 4);
      bf16x8 a8;
#pragma unroll
      for (int j = 0; j < 4; ++j) { a8[j] = (__bf16)f0[j]; a8[j + 4] = (__bf16)f1[j]; }
      ((u16x8*)As)[sr * 4 + (sc ^ ((sr >> 1) & 3))] = __builtin_bit_cast(u16x8, a8);

      const float* wp = W + (size_t)(col0 + sr) * DD + kk * 32 + sc * 8;
      f32x4 w0 = *(const f32x4*)wp;
      f32x4 w1 = *(const f32x4*)(wp + 4);
      bf16x8 w8;
#pragma unroll
      for (int j = 0; j < 4; ++j) { w8[j] = (__bf16)w0[j]; w8[j + 4] = (__bf16)w1[j]; }
      ((u16x8*)Ws)[sr * 4 + (sc ^ ((sr >> 1) & 3))] = __builtin_bit_cast(u16x8, w8);
    }
    __syncthreads();
    const int arow = 16 * w + c;
    u16x8 af = ((u16x8*)As)[arow * 4 + (g ^ ((arow >> 1) & 3))];
#pragma unroll
    for (int n = 0; n < 4; ++n) {
      const int brow = 16 * n + c;
      u16x8 wf = ((u16x8*)Ws)[brow * 4 + (g ^ ((brow >> 1) & 3))];
      acc[n] = mfma16(af, wf, acc[n]);
    }
  }

  // D layout: row = 4*(lane>>4)+r, col = lane&15 (m89-verified)
  if (slot == 3) {
    // transposed store: vhT[(b*256 + col)*1024 + s], rows r are consecutive s
    const int row_base = row0 + 16 * w + 4 * g;
    const int bb = row_base >> 10;
    const int s0 = row_base & 1023;
#pragma unroll
    for (int n = 0; n < 4; ++n) {
      const int col = col0 + 16 * n + c;
      bf16x4 pv;
#pragma unroll
      for (int r = 0; r < 4; ++r) pv[r] = (__bf16)acc[n][r];
      *(u16x4*)(vhT + (size_t)(bb * 256 + col) * SS + s0) =
          __builtin_bit_cast(u16x4, pv);
    }
  } else {
#pragma unroll
    for (int n = 0; n < 4; ++n) {
#pragma unroll
      for (int r = 0; r < 4; ++r) {
        const int row = row0 + 16 * w + 4 * g + r;
        const int col = col0 + 16 * n + c;
        const size_t idx = (size_t)row * DD + col;
        const float val = acc[n][r];
        if (slot == 0)
          qh[idx] = __builtin_bit_cast(unsigned short,
                        (__bf16)(val * 0.17677669529663687f));  // DH^-0.5
        else if (slot == 1)
          sig[idx] = __builtin_bit_cast(unsigned short,
                         (__bf16)(1.0f / (1.0f + __expf(-(val + bg[col])))));
        else
          kh[idx] = __builtin_bit_cast(unsigned short, (__bf16)val);
      }
    }
  }
}

// ---------------------------------------------------------------------------
// Flash attention, swapped-operand form. 1D grid 1024 blocks, 512 threads =
// 8 waves: grp = w>>2 picks kv half [grp*512, +512), wq = w&3 picks 16 q rows.
// XCD swizzle: widx = (bid&7)*128 + bid>>3; h = widx>>7 -> each XCD owns one
// head (bias slice L2-resident; FETCH ~31MB confirmed r4/r5).
// S^T = mfma(K, Q): lane holds S[q=c][kv=16t+4g+r] -> softmax lane-local.
// O^T = mfma(V^T, P^T): acc[dt][r] = O^T[dh=16dt+4g+r][q=c].
// Each group: single-buffered K [64][32] + V^T [32][64] LDS (XOR-swizzled),
// reg-staged prefetch, 2 barriers/tile, 8 tiles. Partials merged in LDS:
// M=max(m0,m1); O=(e^{m0-M}O0+e^{m1-M}O1)/(l0 e^{m0-M}+l1 e^{m1-M}).
// Defer-max (T13): common path has zero cross-lane ops.
// ---------------------------------------------------------------------------
__global__ __launch_bounds__(512, 4) void attn_kernel(
    const unsigned short* __restrict__ qh, const unsigned short* __restrict__ kh,
    const unsigned short* __restrict__ vhT, const unsigned short* __restrict__ sig,
    const float* __restrict__ mask, const float* __restrict__ bias,
    unsigned short* __restrict__ og) {
  const int bid = blockIdx.x;
  const int widx = (bid & 7) * 128 + (bid >> 3);
  const int h = widx >> 7, b = (widx >> 4) & 7, qt = widx & 15;
  const int tid = threadIdx.x;
  const int w = tid >> 6, lane = tid & 63, g = lane >> 4, c = lane & 15;
  const int grp = w >> 2, wq = w & 3;

  __shared__ alignas(16) unsigned short Ks[2][64 * 32];   // [kv][dh] swizzled
  __shared__ alignas(16) unsigned short Vt[2][32 * 64];   // [dh][kv] swizzled
  __shared__ alignas(16) unsigned short Ps[8][16 * 64];   // per-wave P tile
  __shared__ float MLs[4][16][2];                         // grp1 (m,l) per q
  u16x8* Ks16 = (u16x8*)Ks[grp];
  u16x8* Vt16 = (u16x8*)Vt[grp];
  unsigned short* P = Ps[w];

  const int q0 = qt * 64 + wq * 16;
  // Q fragment (B operand): B[col=c][k=8g+i] = Q[q0+c][dh=8g+i]
  const u16x8 qf =
      *(const u16x8*)(qh + (size_t)(b * SS + q0 + c) * DD + h * DHD + g * 8);

  const f32x4 zero = {0.f, 0.f, 0.f, 0.f};
  f32x4 acc[2] = {zero, zero};
  float m_r = -1e30f, l_r = 0.f;   // partial softmax state (this lane's kv set)

  const int kvbase = grp * 512;
  const float* maskb = mask + b * SS + kvbase;
  const float* biasb = bias + (size_t)(h * SS + q0 + c) * SS + kvbase;

  // staging: 256 threads per group each own one 16B chunk of K and V
  const int ltid = tid & 255;
  const int krow = ltid >> 2, kj = ltid & 3;   // K: 64 rows x 4 chunks
  const int vrow = ltid >> 3, vj = ltid & 7;   // V: 32 rows x 8 chunks
  const unsigned short* kg =
      kh + (size_t)(b * SS + kvbase + krow) * DD + h * DHD + kj * 8;
  const unsigned short* vg =
      vhT + (size_t)((b * HH + h) * DHD + vrow) * SS + kvbase + vj * 8;
  const int kslot = krow * 4 + (kj ^ ((krow >> 1) & 3));
  const int vslot = vrow * 8 + (vj ^ (vrow & 7));

  // prologue: stage tile 0
  Ks16[kslot] = *(const u16x8*)kg;
  Vt16[vslot] = *(const u16x8*)vg;
  __syncthreads();

#pragma unroll 1
  for (int kt = 0; kt < 8; ++kt) {
    const int kv0 = kt * 64;
    // next tile's global loads issue early; vmcnt waits land at the ds_write
    u16x8 kreg, vreg;
    if (kt < 7) {
      kreg = *(const u16x8*)(kg + (size_t)(kv0 + 64) * DD);
      vreg = *(const u16x8*)(vg + kv0 + 64);
    }

    // S^T tile: sv[t][r] = S[q=c][kv=kvbase+kv0+16t+4g+r]
    f32x4 sv[4];
#pragma unroll
    for (int t = 0; t < 4; ++t) {
      const u16x8 kf = Ks16[(16 * t + c) * 4 + (g ^ ((c >> 1) & 3))];
      sv[t] = mfma16(kf, qf, zero);
    }
    // + mask + pair bias (direct f32x4 loads; TLP hides L2 latency)
#pragma unroll
    for (int t = 0; t < 4; ++t) {
      const f32x4 bi = *(const f32x4*)(biasb + kv0 + 16 * t + 4 * g);
      const f32x4 mk = *(const f32x4*)(maskb + kv0 + 16 * t + 4 * g);
      sv[t] += bi + mk;
    }
    // defer-max softmax (T13): common path = local max + exp only
    float pm = fmaxf(fmaxf(sv[0][0], sv[0][1]), fmaxf(sv[0][2], sv[0][3]));
#pragma unroll
    for (int t = 1; t < 4; ++t)
      pm = fmaxf(pm, fmaxf(fmaxf(sv[t][0], sv[t][1]), fmaxf(sv[t][2], sv[t][3])));
    if (!__all(pm - m_r <= 8.0f)) {          // fires at kt=0, then ~never
      float mx = fmaxf(pm, __shfl_xor(pm, 16));
      mx = fmaxf(mx, __shfl_xor(mx, 32));
      const float mnew = fmaxf(m_r, mx);
      const float scale = __expf(m_r - mnew);
      l_r *= scale;
      acc[0] *= scale;
      acc[1] *= scale;
      m_r = mnew;
    }
    float ps = 0.f;
#pragma unroll
    for (int t = 0; t < 4; ++t)
#pragma unroll
      for (int r = 0; r < 4; ++r) {
        const float p = __expf(sv[t][r] - m_r);
        sv[t][r] = p;
        ps += p;
      }
    l_r += ps;
    // P -> per-wave LDS, 16B-chunk XOR swizzle
#pragma unroll
    for (int t = 0; t < 4; ++t) {
      bf16x4 pv;
#pragma unroll
      for (int r = 0; r < 4; ++r) pv[r] = (__bf16)sv[t][r];
      const int n = 2 * t + (g >> 1);
      *(u16x4*)(P + c * 64 + ((n ^ (c & 7)) << 3) + ((g & 1) << 2)) =
          __builtin_bit_cast(u16x4, pv);
    }
    // O^T += V^T P^T  (wave-internal LDS RAW; compiler inserts lgkmcnt)
#pragma unroll
    for (int s2 = 0; s2 < 2; ++s2) {
      const u16x8 pf =
          *(const u16x8*)(P + c * 64 + (((4 * s2 + g) ^ (c & 7)) << 3));
#pragma unroll
      for (int dt = 0; dt < 2; ++dt) {
        const u16x8 vf = Vt16[(16 * dt + c) * 8 + ((s2 * 4 + g) ^ (c & 7))];
        acc[dt] = mfma16(vf, pf, acc[dt]);
      }
    }
    // publish next tile
    if (kt < 7) {
      __syncthreads();            // everyone in both groups done reading
      Ks16[kslot] = kreg;
      Vt16[vslot] = vreg;
      __syncthreads();            // next tile visible
    }
  }

  // combine partial l across the 4 g-lanes (same q=c)
  float l_w = l_r + __shfl_xor(l_r, 16);
  l_w += __shfl_xor(l_w, 32);

  // merge the two kv-half partials through LDS (reuse Ps)
  if (grp == 1) {
    float* MB = (float*)Ps[w];    // 16q x 32dh f32 = 2KB, chunk-swizzled
#pragma unroll
    for (int dt = 0; dt < 2; ++dt)
#pragma unroll
      for (int r = 0; r < 4; ++r)
        MB[c * 32 + (((4 * dt + g) ^ (c & 7)) << 2) + r] = acc[dt][r];
    if (g == 0) { MLs[wq][c][0] = m_r; MLs[wq][c][1] = l_w; }
  }
  __syncthreads();
  if (grp == 0) {
    const float m1 = MLs[wq][c][0], l1 = MLs[wq][c][1];
    const float* MB = (const float*)Ps[w + 4];
    const float M = fmaxf(m_r, m1);
    const float e0 = __expf(m_r - M), e1 = __expf(m1 - M);
    const float inv = 1.0f / (l_w * e0 + l1 * e1);
#pragma unroll
    for (int dt = 0; dt < 2; ++dt) {
      const f32x4 a1 =
          *(const f32x4*)(MB + c * 32 + (((4 * dt + g) ^ (c & 7)) << 2));
      const size_t idx =
          (size_t)(b * SS + q0 + c) * DD + h * DHD + 16 * dt + 4 * g;
      const u16x4 sg = *(const u16x4*)(sig + idx);
      bf16x4 ov;
#pragma unroll
      for (int r = 0; r < 4; ++r)
        ov[r] = (__bf16)((acc[dt][r] * e0 + a1[r] * e1) * inv * b2f(sg[r]));
      *(u16x4*)(og + idx) = __builtin_bit_cast(u16x4, ov);
    }
  }
}

// ---------------------------------------------------------------------------
// Output projection: out[8192,256] = og[8192,256] * Wo[256,256]^T (fp32 out)
// ---------------------------------------------------------------------------
__global__ __launch_bounds__(256) void outproj_kernel(
    const unsigned short* __restrict__ og, const float* __restrict__ Wo,
    float* __restrict__ out) {
  const int row0 = blockIdx.x * 64, col0 = blockIdx.y * 64;
  const int tid = threadIdx.x;
  const int w = tid >> 6, lane = tid & 63, g = lane >> 4, c = lane & 15;
  const int sr = tid >> 2, sc = tid & 3;

  __shared__ alignas(16) unsigned short As[64 * 32];
  __shared__ alignas(16) unsigned short Ws[64 * 32];

  const f32x4 zero = {0.f, 0.f, 0.f, 0.f};
  f32x4 acc[4] = {zero, zero, zero, zero};

  for (int kk = 0; kk < 8; ++kk) {
    __syncthreads();
    {
      const unsigned short* ap = og + (size_t)(row0 + sr) * DD + kk * 32 + sc * 8;
      ((u16x8*)As)[sr * 4 + (sc ^ ((sr >> 1) & 3))] = *(const u16x8*)ap;

      const float* wp = Wo + (size_t)(col0 + sr) * DD + kk * 32 + sc * 8;
      f32x4 w0 = *(const f32x4*)wp;
      f32x4 w1 = *(const f32x4*)(wp + 4);
      bf16x8 w8;
#pragma unroll
      for (int j = 0; j < 4; ++j) { w8[j] = (__bf16)w0[j]; w8[j + 4] = (__bf16)w1[j]; }
      ((u16x8*)Ws)[sr * 4 + (sc ^ ((sr >> 1) & 3))] = __builtin_bit_cast(u16x8, w8);
    }
    __syncthreads();
    const int arow = 16 * w + c;
    u16x8 af = ((u16x8*)As)[arow * 4 + (g ^ ((arow >> 1) & 3))];
#pragma unroll
    for (int n = 0; n < 4; ++n) {
      const int brow = 16 * n + c;
      u16x8 wf = ((u16x8*)Ws)[brow * 4 + (g ^ ((brow >> 1) & 3))];
      acc[n] = mfma16(af, wf, acc[n]);
    }
  }

#pragma unroll
  for (int n = 0; n < 4; ++n) {
#pragma unroll
    for (int r = 0; r < 4; ++r) {
      const int row = row0 + 16 * w + 4 * g + r;
      const int col = col0 + 16 * n + c;
      out[(size_t)row * DD + col] = acc[n][r];
    }
  }
}

extern "C" void kernel_launch(void* const* d_in, const int* in_sizes, int n_in,
                              void* d_out, int out_size, void* d_ws,
                              size_t ws_size, hipStream_t stream) {
  const float* q    = (const float*)d_in[0];
  const float* k    = (const float*)d_in[1];
  const float* v    = (const float*)d_in[2];
  const float* mask = (const float*)d_in[3];
  const float* bias = (const float*)d_in[4];
  const float* Wq   = (const float*)d_in[5];
  const float* Wk   = (const float*)d_in[6];
  const float* Wv   = (const float*)d_in[7];
  const float* Wg   = (const float*)d_in[8];
  const float* bg   = (const float*)d_in[9];
  const float* Wo   = (const float*)d_in[10];
  float* out = (float*)d_out;

  char* ws = (char*)d_ws;
  unsigned short* qh  = (unsigned short*)(ws);               // 4 MB bf16
  unsigned short* kh  = (unsigned short*)(ws + (4u << 20));  // 4 MB
  unsigned short* vhT = (unsigned short*)(ws + (8u << 20));  // 4 MB (transposed)
  unsigned short* sig = (unsigned short*)(ws + (12u << 20)); // 4 MB
  unsigned short* og  = (unsigned short*)(ws + (16u << 20)); // 4 MB

  hipLaunchKernelGGL(proj_kernel, dim3(128, 4, 4), dim3(256), 0, stream,
                     q, k, v, Wq, Wg, Wk, Wv, bg, qh, kh, vhT, sig);
  hipLaunchKernelGGL(attn_kernel, dim3(1024), dim3(512), 0, stream,
                     qh, kh, vhT, sig, mask, bias, og);
  hipLaunchKernelGGL(outproj_kernel, dim3(128, 4), dim3(256), 0, stream,
                     og, Wo, out);
}

// Round 8
// 80.240 us; speedup vs baseline: 1.2805x; 1.0665x over previous
//
#include <hip/hip_runtime.h>

// Gated pair-bias attention (AlphaFold-style), MI355X gfx950.
// B=8 S=1024 D=256 H=8 DH=32. All GEMM-shaped work in bf16 MFMA 16x16x32.
//
// Pipeline:
//   proj_kernel   : qh=(q Wq^T)*norm, sig=sigmoid(q Wg^T + bg), kh=k Wk^T,
//                   vhT = (v Wv^T)^T per (b,h)  [dh][s]               (bf16 in ws)
//   attn_kernel   : flash attention, swapped-operand form (S^T and O^T).
//                   KV-tile = 256 (4 tiles total): 32-deep bias/mask MLP batch,
//                   16 independent S-MFMAs/tile, DMA double-buffer, ONE barrier
//                   per tile (4 total vs 30 in r5). ILP over TLP.
//   outproj_kernel: out = og Wo^T  (fp32 to d_out)

typedef __attribute__((ext_vector_type(4))) float f32x4;
typedef __attribute__((ext_vector_type(8))) unsigned short u16x8;
typedef __attribute__((ext_vector_type(4))) unsigned short u16x4;
typedef __attribute__((ext_vector_type(8))) __bf16 bf16x8;
typedef __attribute__((ext_vector_type(4))) __bf16 bf16x4;

#define BB 8
#define SS 1024
#define DD 256
#define HH 8
#define DHD 32

__device__ __forceinline__ float b2f(unsigned short s) {
  unsigned u = ((unsigned)s) << 16;
  return __builtin_bit_cast(float, u);
}
__device__ __forceinline__ f32x4 mfma16(u16x8 a, u16x8 b, f32x4 c) {
  return __builtin_amdgcn_mfma_f32_16x16x32_bf16(
      __builtin_bit_cast(bf16x8, a), __builtin_bit_cast(bf16x8, b), c, 0, 0, 0);
}

// async global->LDS, 16B per lane; dest = wave-uniform base + lane*16 (linear).
__device__ __forceinline__ void gload_lds16(const unsigned short* gsrc,
                                            unsigned short* ldst) {
#if __has_builtin(__builtin_amdgcn_global_load_lds)
  __builtin_amdgcn_global_load_lds(
      (const __attribute__((address_space(1))) unsigned int*)gsrc,
      (__attribute__((address_space(3))) unsigned int*)ldst, 16, 0, 0);
#else
  *(u16x8*)ldst = *(const u16x8*)gsrc;
#endif
}

// ---------------------------------------------------------------------------
// Projections: C[8192,256] = A[8192,256] * W[256,256]^T  (einsum bsd,ed->bse)
// grid (128 row-tiles, 4 col-tiles, 4 slots), 256 threads (4 waves).
// Tile 64x64, K-step 32. LDS chunks (16B) XOR-swizzled: chunk ^= (row>>1)&3.
// slot 3 (v) stores TRANSPOSED per (b,h): vhT[((b*H+h)*DH+dh)*S + s].
// ---------------------------------------------------------------------------
__global__ __launch_bounds__(256) void proj_kernel(
    const float* __restrict__ q, const float* __restrict__ k,
    const float* __restrict__ v,
    const float* __restrict__ Wq, const float* __restrict__ Wg,
    const float* __restrict__ Wk, const float* __restrict__ Wv,
    const float* __restrict__ bg,
    unsigned short* __restrict__ qh, unsigned short* __restrict__ kh,
    unsigned short* __restrict__ vhT, unsigned short* __restrict__ sig) {
  const int slot = blockIdx.z;
  const float* A = (slot <= 1) ? q : (slot == 2 ? k : v);
  const float* W = (slot == 0) ? Wq : (slot == 1 ? Wg : (slot == 2 ? Wk : Wv));
  const int row0 = blockIdx.x * 64, col0 = blockIdx.y * 64;
  const int tid = threadIdx.x;
  const int w = tid >> 6, lane = tid & 63, g = lane >> 4, c = lane & 15;
  const int sr = tid >> 2, sc = tid & 3;   // staging: row 0..63, chunk 0..3

  __shared__ alignas(16) unsigned short As[64 * 32];
  __shared__ alignas(16) unsigned short Ws[64 * 32];

  const f32x4 zero = {0.f, 0.f, 0.f, 0.f};
  f32x4 acc[4] = {zero, zero, zero, zero};

  for (int kk = 0; kk < 8; ++kk) {
    __syncthreads();
    {
      const float* ap = A + (size_t)(row0 + sr) * DD + kk * 32 + sc * 8;
      f32x4 f0 = *(const f32x4*)ap;
      f32x4 f1 = *(const f32x4*)(ap + 4);
      bf16x8 a8;
#pragma unroll
      for (int j = 0; j < 4; ++j) { a8[j] = (__bf16)f0[j]; a8[j + 4] = (__bf16)f1[j]; }
      ((u16x8*)As)[sr * 4 + (sc ^ ((sr >> 1) & 3))] = __builtin_bit_cast(u16x8, a8);

      const float* wp = W + (size_t)(col0 + sr) * DD + kk * 32 + sc * 8;
      f32x4 w0 = *(const f32x4*)wp;
      f32x4 w1 = *(const f32x4*)(wp + 4);
      bf16x8 w8;
#pragma unroll
      for (int j = 0; j < 4; ++j) { w8[j] = (__bf16)w0[j]; w8[j + 4] = (__bf16)w1[j]; }
      ((u16x8*)Ws)[sr * 4 + (sc ^ ((sr >> 1) & 3))] = __builtin_bit_cast(u16x8, w8);
    }
    __syncthreads();
    const int arow = 16 * w + c;
    u16x8 af = ((u16x8*)As)[arow * 4 + (g ^ ((arow >> 1) & 3))];
#pragma unroll
    for (int n = 0; n < 4; ++n) {
      const int brow = 16 * n + c;
      u16x8 wf = ((u16x8*)Ws)[brow * 4 + (g ^ ((brow >> 1) & 3))];
      acc[n] = mfma16(af, wf, acc[n]);
    }
  }

  // D layout: row = 4*(lane>>4)+r, col = lane&15 (m89-verified)
  if (slot == 3) {
    // transposed store: vhT[(b*256 + col)*1024 + s], rows r are consecutive s
    const int row_base = row0 + 16 * w + 4 * g;
    const int bb = row_base >> 10;
    const int s0 = row_base & 1023;
#pragma unroll
    for (int n = 0; n < 4; ++n) {
      const int col = col0 + 16 * n + c;
      bf16x4 pv;
#pragma unroll
      for (int r = 0; r < 4; ++r) pv[r] = (__bf16)acc[n][r];
      *(u16x4*)(vhT + (size_t)(bb * 256 + col) * SS + s0) =
          __builtin_bit_cast(u16x4, pv);
    }
  } else {
#pragma unroll
    for (int n = 0; n < 4; ++n) {
#pragma unroll
      for (int r = 0; r < 4; ++r) {
        const int row = row0 + 16 * w + 4 * g + r;
        const int col = col0 + 16 * n + c;
        const size_t idx = (size_t)row * DD + col;
        const float val = acc[n][r];
        if (slot == 0)
          qh[idx] = __builtin_bit_cast(unsigned short,
                        (__bf16)(val * 0.17677669529663687f));  // DH^-0.5
        else if (slot == 1)
          sig[idx] = __builtin_bit_cast(unsigned short,
                         (__bf16)(1.0f / (1.0f + __expf(-(val + bg[col])))));
        else
          kh[idx] = __builtin_bit_cast(unsigned short, (__bf16)val);
      }
    }
  }
}

// ---------------------------------------------------------------------------
// Flash attention, swapped-operand form. 1D grid 1024 blocks, 256 threads =
// 4 waves; wave w owns q rows [qt*64+16w, +16); lane's q = base + (lane&15).
// XCD swizzle: widx = (bid&7)*128 + bid>>3; h = widx>>7 -> each XCD owns one
// head (bias slice L2-resident).
// S^T = mfma(K, Q): lane holds S[q=c][kv=...+16t+4g+r] -> softmax lane-local.
// O^T = mfma(V^T, P^T): acc[dt][r] = O^T[dh=16dt+4g+r][q=c].
// KV-tile = 256: K [256][32] + V^T [32][256] double-buffered via
// global_load_lds DMA (linear dest slot s=tid(+256i), inverse-swizzled SOURCE,
// swizzled read — rule #21). ONE barrier + one implicit vmcnt drain per tile.
// Per tile: 4 groups of {4 S-MFMA, bias+mask add, defer-max exp, P round-trip,
// 4 PV-MFMA} — groups have no barriers, overlap MFMA/VALU/LDS pipes.
// ---------------------------------------------------------------------------
__global__ __launch_bounds__(256, 2) void attn_kernel(
    const unsigned short* __restrict__ qh, const unsigned short* __restrict__ kh,
    const unsigned short* __restrict__ vhT, const unsigned short* __restrict__ sig,
    const float* __restrict__ mask, const float* __restrict__ bias,
    unsigned short* __restrict__ og) {
  const int bid = blockIdx.x;
  const int widx = (bid & 7) * 128 + (bid >> 3);
  const int h = widx >> 7, b = (widx >> 4) & 7, qt = widx & 15;
  const int tid = threadIdx.x;
  const int w = tid >> 6, lane = tid & 63, g = lane >> 4, c = lane & 15;

  __shared__ alignas(16) unsigned short KsB[2][256 * 32];  // [kv][dh] swizzled
  __shared__ alignas(16) unsigned short VtB[2][32 * 256];  // [dh][kv] swizzled
  __shared__ alignas(16) unsigned short Ps[4][16 * 64];    // per-wave P tile
  unsigned short* P = Ps[w];

  const int q0 = qt * 64 + w * 16;
  // Q fragment (B operand): B[col=c][k=8g+i] = Q[q0+c][dh=8g+i]
  const u16x8 qf =
      *(const u16x8*)(qh + (size_t)(b * SS + q0 + c) * DD + h * DHD + g * 8);

  const f32x4 zero = {0.f, 0.f, 0.f, 0.f};
  f32x4 acc[2] = {zero, zero};
  float m_r = -1e30f, l_r = 0.f;   // defer-max state, lane-local partial l

  const float* maskb = mask + b * SS;
  const float* biasb = bias + (size_t)(h * SS + q0 + c) * SS;

  // DMA staging: 2048 chunks of 16B per tile (K 1024 + V 1024), 8 per thread.
  // K: slot s -> (krow = s>>2, phys chunk s&3) holds logical chunk
  //    (s&3)^((krow>>1)&3).  V: slot s -> (vr = s>>5, phys col s&31) holds
  //    logical col (jp&24)|((jp&7)^(vr&7)).
  auto stage = [&](int buf, int kv0) {
    unsigned short* Kb = KsB[buf];
    unsigned short* Vb = VtB[buf];
#pragma unroll
    for (int i = 0; i < 4; ++i) {
      const int s = i * 256 + tid;
      const int krow = s >> 2, kc = s & 3;
      const int klc = kc ^ ((krow >> 1) & 3);
      gload_lds16(kh + (size_t)(b * SS + kv0 + krow) * DD + h * DHD + klc * 8,
                  Kb + s * 8);
      const int vr = s >> 5, jp = s & 31;
      const int jl = (jp & 24) | ((jp & 7) ^ (vr & 7));
      gload_lds16(vhT + (size_t)((b * HH + h) * DHD + vr) * SS + kv0 + jl * 8,
                  Vb + s * 8);
    }
  };

  // prologue: stage tile 0
  stage(0, 0);
  __syncthreads();   // drains vmcnt (DMA) before reads

#pragma unroll 1
  for (int kt = 0; kt < 4; ++kt) {
    const int cur = kt & 1;
    const int kv0 = kt * 256;
    if (kt < 3) stage(cur ^ 1, kv0 + 256);   // DMA flies under compute

    const u16x8* Ks16 = (const u16x8*)KsB[cur];
    const u16x8* Vt16 = (const u16x8*)VtB[cur];

#pragma unroll
    for (int gr = 0; gr < 4; ++gr) {
      const int kvg = kv0 + gr * 64;
      // S^T group: sv[t][r] = S[q=c][kv=kvg+16t+4g+r]  (4 independent MFMAs)
      f32x4 sv[4];
#pragma unroll
      for (int t = 0; t < 4; ++t) {
        const u16x8 kf =
            Ks16[(gr * 64 + 16 * t + c) * 4 + (g ^ ((c >> 1) & 3))];
        sv[t] = mfma16(kf, qf, zero);
      }
      // + mask + pair bias (f32x4; compiler hoists/batches across groups)
#pragma unroll
      for (int t = 0; t < 4; ++t) {
        const f32x4 bi = *(const f32x4*)(biasb + kvg + 16 * t + 4 * g);
        const f32x4 mk = *(const f32x4*)(maskb + kvg + 16 * t + 4 * g);
        sv[t] += bi + mk;
      }
      // defer-max softmax (T13): common path = local max + exp only
      float pm = fmaxf(fmaxf(sv[0][0], sv[0][1]), fmaxf(sv[0][2], sv[0][3]));
#pragma unroll
      for (int t = 1; t < 4; ++t)
        pm = fmaxf(pm,
                   fmaxf(fmaxf(sv[t][0], sv[t][1]), fmaxf(sv[t][2], sv[t][3])));
      if (!__all(pm - m_r <= 8.0f)) {        // fires on first group, then ~never
        float mx = fmaxf(pm, __shfl_xor(pm, 16));
        mx = fmaxf(mx, __shfl_xor(mx, 32));
        const float mnew = fmaxf(m_r, mx);
        const float scale = __expf(m_r - mnew);
        l_r *= scale;
        acc[0] *= scale;
        acc[1] *= scale;
        m_r = mnew;
      }
      float ps = 0.f;
#pragma unroll
      for (int t = 0; t < 4; ++t)
#pragma unroll
        for (int r = 0; r < 4; ++r) {
          const float p = __expf(sv[t][r] - m_r);
          sv[t][r] = p;
          ps += p;
        }
      l_r += ps;
      // P -> per-wave LDS, 16B-chunk XOR swizzle
#pragma unroll
      for (int t = 0; t < 4; ++t) {
        bf16x4 pv;
#pragma unroll
        for (int r = 0; r < 4; ++r) pv[r] = (__bf16)sv[t][r];
        const int n = 2 * t + (g >> 1);
        *(u16x4*)(P + c * 64 + ((n ^ (c & 7)) << 3) + ((g & 1) << 2)) =
            __builtin_bit_cast(u16x4, pv);
      }
      // O^T += V^T P^T  (wave-internal LDS RAW; compiler inserts lgkmcnt)
#pragma unroll
      for (int s2 = 0; s2 < 2; ++s2) {
        const u16x8 pf =
            *(const u16x8*)(P + c * 64 + (((4 * s2 + g) ^ (c & 7)) << 3));
#pragma unroll
        for (int dt = 0; dt < 2; ++dt) {
          const u16x8 vf =
              Vt16[(16 * dt + c) * 32 + gr * 8 + ((4 * s2 + g) ^ (c & 7))];
          acc[dt] = mfma16(vf, pf, acc[dt]);
        }
      }
    }
    __syncthreads();   // drains DMA for next buffer + all waves done with cur
  }

  // epilogue: combine partial l across the 4 g-lanes (same q=c), gate, store
  float l = l_r + __shfl_xor(l_r, 16);
  l += __shfl_xor(l, 32);
  const float inv = 1.0f / l;
#pragma unroll
  for (int dt = 0; dt < 2; ++dt) {
    const size_t idx =
        (size_t)(b * SS + q0 + c) * DD + h * DHD + 16 * dt + 4 * g;
    const u16x4 sg = *(const u16x4*)(sig + idx);
    bf16x4 ov;
#pragma unroll
    for (int r = 0; r < 4; ++r) ov[r] = (__bf16)(acc[dt][r] * inv * b2f(sg[r]));
    *(u16x4*)(og + idx) = __builtin_bit_cast(u16x4, ov);
  }
}

// ---------------------------------------------------------------------------
// Output projection: out[8192,256] = og[8192,256] * Wo[256,256]^T (fp32 out)
// ---------------------------------------------------------------------------
__global__ __launch_bounds__(256) void outproj_kernel(
    const unsigned short* __restrict__ og, const float* __restrict__ Wo,
    float* __restrict__ out) {
  const int row0 = blockIdx.x * 64, col0 = blockIdx.y * 64;
  const int tid = threadIdx.x;
  const int w = tid >> 6, lane = tid & 63, g = lane >> 4, c = lane & 15;
  const int sr = tid >> 2, sc = tid & 3;

  __shared__ alignas(16) unsigned short As[64 * 32];
  __shared__ alignas(16) unsigned short Ws[64 * 32];

  const f32x4 zero = {0.f, 0.f, 0.f, 0.f};
  f32x4 acc[4] = {zero, zero, zero, zero};

  for (int kk = 0; kk < 8; ++kk) {
    __syncthreads();
    {
      const unsigned short* ap = og + (size_t)(row0 + sr) * DD + kk * 32 + sc * 8;
      ((u16x8*)As)[sr * 4 + (sc ^ ((sr >> 1) & 3))] = *(const u16x8*)ap;

      const float* wp = Wo + (size_t)(col0 + sr) * DD + kk * 32 + sc * 8;
      f32x4 w0 = *(const f32x4*)wp;
      f32x4 w1 = *(const f32x4*)(wp + 4);
      bf16x8 w8;
#pragma unroll
      for (int j = 0; j < 4; ++j) { w8[j] = (__bf16)w0[j]; w8[j + 4] = (__bf16)w1[j]; }
      ((u16x8*)Ws)[sr * 4 + (sc ^ ((sr >> 1) & 3))] = __builtin_bit_cast(u16x8, w8);
    }
    __syncthreads();
    const int arow = 16 * w + c;
    u16x8 af = ((u16x8*)As)[arow * 4 + (g ^ ((arow >> 1) & 3))];
#pragma unroll
    for (int n = 0; n < 4; ++n) {
      const int brow = 16 * n + c;
      u16x8 wf = ((u16x8*)Ws)[brow * 4 + (g ^ ((brow >> 1) & 3))];
      acc[n] = mfma16(af, wf, acc[n]);
    }
  }

#pragma unroll
  for (int n = 0; n < 4; ++n) {
#pragma unroll
    for (int r = 0; r < 4; ++r) {
      const int row = row0 + 16 * w + 4 * g + r;
      const int col = col0 + 16 * n + c;
      out[(size_t)row * DD + col] = acc[n][r];
    }
  }
}

extern "C" void kernel_launch(void* const* d_in, const int* in_sizes, int n_in,
                              void* d_out, int out_size, void* d_ws,
                              size_t ws_size, hipStream_t stream) {
  const float* q    = (const float*)d_in[0];
  const float* k    = (const float*)d_in[1];
  const float* v    = (const float*)d_in[2];
  const float* mask = (const float*)d_in[3];
  const float* bias = (const float*)d_in[4];
  const float* Wq   = (const float*)d_in[5];
  const float* Wk   = (const float*)d_in[6];
  const float* Wv   = (const float*)d_in[7];
  const float* Wg   = (const float*)d_in[8];
  const float* bg   = (const float*)d_in[9];
  const float* Wo   = (const float*)d_in[10];
  float* out = (float*)d_out;

  char* ws = (char*)d_ws;
  unsigned short* qh  = (unsigned short*)(ws);               // 4 MB bf16
  unsigned short* kh  = (unsigned short*)(ws + (4u << 20));  // 4 MB
  unsigned short* vhT = (unsigned short*)(ws + (8u << 20));  // 4 MB (transposed)
  unsigned short* sig = (unsigned short*)(ws + (12u << 20)); // 4 MB
  unsigned short* og  = (unsigned short*)(ws + (16u << 20)); // 4 MB

  hipLaunchKernelGGL(proj_kernel, dim3(128, 4, 4), dim3(256), 0, stream,
                     q, k, v, Wq, Wg, Wk, Wv, bg, qh, kh, vhT, sig);
  hipLaunchKernelGGL(attn_kernel, dim3(1024), dim3(256), 0, stream,
                     qh, kh, vhT, sig, mask, bias, og);
  hipLaunchKernelGGL(outproj_kernel, dim3(128, 4), dim3(256), 0, stream,
                     og, Wo, out);
}